// Round 13
// baseline (174.478 us; speedup 1.0000x reference)
//
#include <hip/hip_runtime.h>
#include <hip/hip_fp16.h>
#include <stdint.h>

#define NROWS 8192
#define DIM 64
#define EPS 0.1f

typedef float f32x4 __attribute__((ext_vector_type(4)));
typedef short s16x8 __attribute__((ext_vector_type(8)));
typedef _Float16 h2 __attribute__((ext_vector_type(2)));

// ---------- helpers ----------

__device__ __forceinline__ float wave_reduce_add(float v) {
  #pragma unroll
  for (int off = 32; off > 0; off >>= 1) v += __shfl_down(v, off, 64);
  return v;
}

// pack two fp32 -> bf16x2 dword by truncation (1 v_perm); x -> low, y -> high.
__device__ __forceinline__ uint32_t pack_bf16_trunc(float x, float y) {
  return __builtin_amdgcn_perm(__float_as_uint(y), __float_as_uint(x), 0x07060302u);
}

// Column permutation: K4 stores columns in pi-order so kgen's per-lane nibbles
// are contiguous. pi shuffles only bits 0..5 (within a 64-col half-tile).
__device__ __forceinline__ int pi_idx(int i) {
  int r = i & 63;
  int tj = r >> 4, quad = (r >> 2) & 3, e = r & 3;
  return (i & ~63) | (quad * 16 + tj * 4 + e);
}

// ---------- fp4 e2m1 encode/decode (block-scaled, scale applied manually) ----

#if __has_builtin(__builtin_amdgcn_cvt_scalef32_pk_f16_fp4)
#define CVT4H(kd, sel) __builtin_amdgcn_cvt_scalef32_pk_f16_fp4((kd), 1.0f, (sel))
#else
__device__ __forceinline__ h2 cvt4h_fb(uint32_t kd, int sel) {
  uint32_t byt  = (kd >> (sel * 8)) & 0xFFu;
  uint32_t selv = (byt & 0xFu) | ((byt >> 4) << 16);
  uint32_t tb = __builtin_amdgcn_perm(0x46444240u, 0x3E3C3800u, selv);
  uint32_t d  = ((tb & 0xFFu) << 8) | ((tb & 0xFF0000u) << 8);
  return __builtin_bit_cast(h2, d);
}
#define CVT4H(kd, sel) cvt4h_fb((kd), (sel))
#endif

#if __has_builtin(__builtin_amdgcn_cvt_scalef32_pk_fp4_f32)
__device__ __forceinline__ uint32_t enc4(float q0, float q1, float q2, float q3) {
  uint32_t pk = __builtin_amdgcn_cvt_scalef32_pk_fp4_f32(0u, q0, q1, 1.0f, 0);
  pk = __builtin_amdgcn_cvt_scalef32_pk_fp4_f32(pk, q2, q3, 1.0f, 1);
  return pk & 0xFFFFu;
}
#else
__device__ __forceinline__ uint32_t enc1(float q) {
  float c = fminf(floorf(2.f * q + 0.5f), 4.f);
  c += (q > 2.5f) ? 1.f : 0.f;
  c += (q > 3.5f) ? 1.f : 0.f;
  return (uint32_t)c;
}
__device__ __forceinline__ uint32_t enc4(float q0, float q1, float q2, float q3) {
  return enc1(q0) | (enc1(q1) << 4) | (enc1(q2) << 8) | (enc1(q3) << 12);
}
#endif

// fast exp of -10*d: exp2(-10*log2(e)*d)
#if __has_builtin(__builtin_amdgcn_exp2f)
#define EXPD(d) __builtin_amdgcn_exp2f(-14.4269504089f * (d))
#else
#define EXPD(d) __expf(-10.0f * (d))
#endif

#define FP4DOT(kd, xv, acc)                                                          \
  acc = __builtin_amdgcn_fdot2(CVT4H((kd), 0), __builtin_bit_cast(h2, (xv).x), acc, false); \
  acc = __builtin_amdgcn_fdot2(CVT4H((kd), 1), __builtin_bit_cast(h2, (xv).y), acc, false); \
  acc = __builtin_amdgcn_fdot2(CVT4H((kd), 2), __builtin_bit_cast(h2, (xv).z), acc, false); \
  acc = __builtin_amdgcn_fdot2(CVT4H((kd), 3), __builtin_bit_cast(h2, (xv).w), acc, false);

// final-pass dot: s1b += k^*x via CVT; t2b += (k^*ln k^)*x via exact-f16 nibble LUT.
#define FIN1(kd, xd_, sel)                                                           \
  {                                                                                  \
    uint32_t byt  = ((kd) >> ((sel) * 8)) & 0xFFu;                                   \
    uint32_t selv = (byt & 0xFu) | ((byt & 0xF0u) << 12);                            \
    uint32_t hi = __builtin_amdgcn_perm(0x4945423Du, 0x3800B500u, selv);             \
    uint32_t lo = __builtin_amdgcn_perm(0x608C978Cu, 0xDE008C00u, selv);             \
    h2 lut = __builtin_bit_cast(h2, lo | (hi << 8));                                 \
    h2 xp  = __builtin_bit_cast(h2, (xd_));                                          \
    s1b = __builtin_amdgcn_fdot2(CVT4H((kd), (sel)), xp, s1b, false);                \
    t2b = __builtin_amdgcn_fdot2(lut, xp, t2b, false);                               \
  }
#define FINDOT(kd, xv) FIN1(kd, (xv).x, 0) FIN1(kd, (xv).y, 1) FIN1(kd, (xv).z, 2) FIN1(kd, (xv).w, 3)

// ---------- rownorm_pack: |row|^2 AND fragment-swizzled bf16 rows --------------
// Pb/Qb layout (1 MB each): chunk (row r, kc c) = 16 B at uint4 index
// ((r>>4)*8 + c)*16 + (r&15) — MFMA fragment order, loaded straight from global.

__global__ __launch_bounds__(256) void rownorm_pack(
    const float* __restrict__ P, const float* __restrict__ Q,
    float* __restrict__ p2, float* __restrict__ q2,
    uint4* __restrict__ Pb, uint4* __restrict__ Qb) {
  int g = blockIdx.x * 256 + threadIdx.x;   // 131072 threads
  int row = g >> 3, sub = g & 7;            // row 0..16383, chunk sub 0..7
  const float* X;
  float* out;
  uint4* Xb;
  int r;
  float sc;
  if (row < NROWS) { X = P; out = p2; Xb = Pb; r = row; sc = -2.f; }
  else             { X = Q; out = q2; Xb = Qb; r = row - NROWS; sc = 1.f; }
  const float4* X4 = (const float4*)(X + (size_t)r * DIM);
  float4 a0 = X4[sub * 2], a1 = X4[sub * 2 + 1];
  float ss = a0.x * a0.x + a0.y * a0.y + a0.z * a0.z + a0.w * a0.w
           + a1.x * a1.x + a1.y * a1.y + a1.z * a1.z + a1.w * a1.w;
  ss += __shfl_xor(ss, 1, 64);
  ss += __shfl_xor(ss, 2, 64);
  ss += __shfl_xor(ss, 4, 64);
  if (sub == 0) out[r] = ss;
  uint4 pk;
  pk.x = pack_bf16_trunc(sc * a0.x, sc * a0.y);
  pk.y = pack_bf16_trunc(sc * a0.z, sc * a0.w);
  pk.z = pack_bf16_trunc(sc * a1.x, sc * a1.y);
  pk.w = pack_bf16_trunc(sc * a1.z, sc * a1.w);
  Xb[(((r >> 4) * 8 + sub) << 4) + (r & 15)] = pk;
}

// ---------- kgen: LDS-free MFMA -> fp4, 1024 threads, 32x64 per wave ----------
// 16 waves/block (guaranteed 4 waves/SIMD via __launch_bounds__(1024)): acc
// shrunk to [2][4] (32 VGPR) so occupancy doubles vs the 64x64-tile version —
// round-11 counters showed kgen latency-bound (VALUBusy 48% @ ~1.6 waves/SIMD).
// Block tile stays 128x256 -> full 128-B K4 line per row, XCD row-striping kept.

__global__ __launch_bounds__(1024) void kgen_kernel(
    const uint4* __restrict__ Pb, const uint4* __restrict__ Qb,
    const float* __restrict__ p2, const float* __restrict__ q2,
    unsigned char* __restrict__ K4, unsigned char* __restrict__ scales,
    float* __restrict__ rspart) {
  const int t  = threadIdx.x;
  const int bi = blockIdx.x * 128;   // row panel (x-fastest -> XCD = panel%8)
  const int bj = blockIdx.y * 256;   // col panel

  const int w        = t >> 6;                // 0..15
  const int lane     = t & 63;
  const int quad     = lane >> 4;
  const int m16      = lane & 15;
  const int wave_row = (w >> 2) * 32;         // 0,32,64,96
  const int wave_col = (w & 3) * 64;          // 0,64,128,192

  const s16x8* Pw = (const s16x8*)Pb;
  const s16x8* Qw = (const s16x8*)Qb;
  const int gp = (bi + wave_row) >> 4;        // 16-row group base
  const int gq = (bj + wave_col) >> 4;

  float pn[2];
  f32x4 qn[4];
  #pragma unroll
  for (int ti = 0; ti < 2; ++ti) pn[ti] = p2[bi + wave_row + ti * 16 + m16];
  #pragma unroll
  for (int tj = 0; tj < 4; ++tj)
    qn[tj] = *(const f32x4*)&q2[bj + wave_col + tj * 16 + quad * 4];

  f32x4 acc[2][4];
  #pragma unroll
  for (int ti = 0; ti < 2; ++ti)
    #pragma unroll
    for (int tj = 0; tj < 4; ++tj) acc[ti][tj] = qn[tj] + pn[ti];

  #pragma unroll
  for (int kstep = 0; kstep < 2; ++kstep) {
    const int kc = kstep * 4 + quad;
    s16x8 af[2], bf[4];
    #pragma unroll
    for (int ti = 0; ti < 2; ++ti)
      af[ti] = Pw[((gp + ti) * 8 + kc) * 16 + m16];
    #pragma unroll
    for (int tj = 0; tj < 4; ++tj)
      bf[tj] = Qw[((gq + tj) * 8 + kc) * 16 + m16];
    #pragma unroll
    for (int ti = 0; ti < 2; ++ti)
      #pragma unroll
      for (int tj = 0; tj < 4; ++tj)
        acc[ti][tj] = __builtin_amdgcn_mfma_f32_16x16x32_bf16(
            bf[tj], af[ti], acc[ti][tj], 0, 0, 0);   // swapped operands
  }

  #pragma unroll
  for (int ti = 0; ti < 2; ++ti) {
    const int row = bi + wave_row + ti * 16 + m16;
    float kv[4][4];
    float mx = 0.f, rs = 0.f;
    #pragma unroll
    for (int tj = 0; tj < 4; ++tj) {
      f32x4 sq = acc[ti][tj];
      kv[tj][0] = EXPD(__builtin_amdgcn_sqrtf(fmaxf(sq.x, 0.f)));
      kv[tj][1] = EXPD(__builtin_amdgcn_sqrtf(fmaxf(sq.y, 0.f)));
      kv[tj][2] = EXPD(__builtin_amdgcn_sqrtf(fmaxf(sq.z, 0.f)));
      kv[tj][3] = EXPD(__builtin_amdgcn_sqrtf(fmaxf(sq.w, 0.f)));
      float mt = fmaxf(fmaxf(kv[tj][0], kv[tj][1]), fmaxf(kv[tj][2], kv[tj][3]));
      mx = fmaxf(mx, mt);
      rs += (kv[tj][0] + kv[tj][1]) + (kv[tj][2] + kv[tj][3]);
    }
    mx = fmaxf(mx, __shfl_xor(mx, 16, 64));
    uint32_t eb = (__float_as_uint(mx) >> 23) - 1u;
    float si = __uint_as_float((254u - eb) << 23);   // 1/S, S = 2^(e-1)
    uint32_t pk0 = enc4(kv[0][0] * si, kv[0][1] * si, kv[0][2] * si, kv[0][3] * si);
    uint32_t pk1 = enc4(kv[1][0] * si, kv[1][1] * si, kv[1][2] * si, kv[1][3] * si);
    uint32_t pk2 = enc4(kv[2][0] * si, kv[2][1] * si, kv[2][2] * si, kv[2][3] * si);
    uint32_t pk3 = enc4(kv[3][0] * si, kv[3][1] * si, kv[3][2] * si, kv[3][3] * si);
    uint2 st = uint2{pk0 | (pk1 << 16), pk2 | (pk3 << 16)};
    *(uint2*)(K4 + (size_t)row * (NROWS / 2) + ((bj + wave_col) >> 1) + quad * 8) = st;
    uint32_t eb2 = (uint32_t)__shfl_xor((int)eb, 32, 64);  // quad0 <- quad2
    if (quad == 0) {
      *(unsigned short*)(scales + (size_t)row * 256 + ((bj + wave_col) >> 5)) =
          (unsigned short)((eb & 0xFFu) | ((eb2 & 0xFFu) << 8));
    }
    float v = rs;
    v += __shfl_xor(v, 16, 64);
    v += __shfl_xor(v, 32, 64);
    if (quad == 0)
      rspart[(size_t)(blockIdx.y * 4 + (w & 3)) * NROWS + row] = v;
  }
}

// v1: reduce 128 rowsum partials per row; vb16[pi(i)] = f16(64 / rowsum[i])
__global__ __launch_bounds__(128) void v1_kernel(const float* __restrict__ rspart,
                                                 unsigned short* __restrict__ vb16) {
  int i = blockIdx.x * 128 + threadIdx.x;
  float s = 0.f;
  #pragma unroll 8
  for (int c = 0; c < 128; ++c) s += rspart[(size_t)c * NROWS + i];
  vb16[pi_idx(i)] = __half_as_ushort(__float2half(64.0f / s));
}

// ---------- matvec: 4 rows x all cols per wave; rows remapped so each block's
// K-panel lives in ITS XCD's L2 (block b -> row panel p with p%8 == b%8) -------

__global__ __launch_bounds__(256) void matvec_fp4(
    const unsigned char* __restrict__ K4, const unsigned char* __restrict__ scales,
    const unsigned short* __restrict__ xin, unsigned short* __restrict__ yout) {
  const int t = threadIdx.x, lane = t & 63, w = t >> 6;
  const int bk = blockIdx.x & 7, j = blockIdx.x >> 3;       // XCD class, intra
  const int panel = ((j >> 3) << 3) | bk;                   // panel%8 == bk
  const int r0 = panel * 128 + (j & 7) * 16 + w * 4;
  const uint4* kr0 = (const uint4*)(K4 + (size_t)r0 * (NROWS / 2));
  const uint4* kr1 = (const uint4*)(K4 + (size_t)(r0 + 1) * (NROWS / 2));
  const uint4* kr2 = (const uint4*)(K4 + (size_t)(r0 + 2) * (NROWS / 2));
  const uint4* kr3 = (const uint4*)(K4 + (size_t)(r0 + 3) * (NROWS / 2));
  const unsigned char* sr0 = scales + (size_t)r0 * 256;
  const unsigned char* sr1 = sr0 + 256;
  const unsigned char* sr2 = sr0 + 512;
  const unsigned char* sr3 = sr0 + 768;
  const uint4* x4 = (const uint4*)xin;

  // chunk 0 preload
  int b = lane;
  uint4 nx0 = x4[b * 4 + 0], nx1 = x4[b * 4 + 1];
  uint4 nx2 = x4[b * 4 + 2], nx3 = x4[b * 4 + 3];
  uint4 nk0 = kr0[b], nk1 = kr1[b], nk2 = kr2[b], nk3 = kr3[b];

  float t0 = 0.f, t1 = 0.f, t2 = 0.f, t3 = 0.f;
  #pragma unroll
  for (int s = 0; s < 4; ++s) {
    uint4 cx0 = nx0, cx1 = nx1, cx2 = nx2, cx3 = nx3;
    uint4 ck0 = nk0, ck1 = nk1, ck2 = nk2, ck3 = nk3;
    uint32_t sb0 = sr0[b], sb1 = sr1[b], sb2 = sr2[b], sb3 = sr3[b];
    if (s < 3) {
      int bn = b + 64;
      nx0 = x4[bn * 4 + 0]; nx1 = x4[bn * 4 + 1];
      nx2 = x4[bn * 4 + 2]; nx3 = x4[bn * 4 + 3];
      nk0 = kr0[bn]; nk1 = kr1[bn]; nk2 = kr2[bn]; nk3 = kr3[bn];
      b = bn;
    }
    float a0, a1;
    a0 = 0.f; a1 = 0.f;
    FP4DOT(ck0.x, cx0, a0) FP4DOT(ck0.y, cx1, a1)
    FP4DOT(ck0.z, cx2, a0) FP4DOT(ck0.w, cx3, a1)
    t0 = fmaf(__uint_as_float(sb0 << 23), a0 + a1, t0);
    a0 = 0.f; a1 = 0.f;
    FP4DOT(ck1.x, cx0, a0) FP4DOT(ck1.y, cx1, a1)
    FP4DOT(ck1.z, cx2, a0) FP4DOT(ck1.w, cx3, a1)
    t1 = fmaf(__uint_as_float(sb1 << 23), a0 + a1, t1);
    a0 = 0.f; a1 = 0.f;
    FP4DOT(ck2.x, cx0, a0) FP4DOT(ck2.y, cx1, a1)
    FP4DOT(ck2.z, cx2, a0) FP4DOT(ck2.w, cx3, a1)
    t2 = fmaf(__uint_as_float(sb2 << 23), a0 + a1, t2);
    a0 = 0.f; a1 = 0.f;
    FP4DOT(ck3.x, cx0, a0) FP4DOT(ck3.y, cx1, a1)
    FP4DOT(ck3.z, cx2, a0) FP4DOT(ck3.w, cx3, a1)
    t3 = fmaf(__uint_as_float(sb3 << 23), a0 + a1, t3);
  }

  t0 = wave_reduce_add(t0);
  t1 = wave_reduce_add(t1);
  t2 = wave_reduce_add(t2);
  t3 = wave_reduce_add(t3);
  if (lane == 0) {
    yout[pi_idx(r0 + 0)] = __half_as_ushort(__float2half(1.0f / t0));
    yout[pi_idx(r0 + 1)] = __half_as_ushort(__float2half(1.0f / t1));
    yout[pi_idx(r0 + 2)] = __half_as_ushort(__float2half(1.0f / t2));
    yout[pi_idx(r0 + 3)] = __half_as_ushort(__float2half(1.0f / t3));
  }
}

// ---------- final_fp4: 2 rows x half-cols per wave, XCD-remapped rows ----------

__global__ __launch_bounds__(256) void final_fp4(
    const unsigned char* __restrict__ K4, const unsigned char* __restrict__ scales,
    const unsigned short* __restrict__ xin, float* __restrict__ partials) {
  const int t = threadIdx.x, lane = t & 63, w = t >> 6;
  const int p = w >> 1, h = w & 1;
  const int bk = blockIdx.x & 7, j = blockIdx.x >> 3;       // j 0..255
  const int panel = ((j >> 5) << 3) | bk;                   // panel%8 == bk
  const int r0 = panel * 128 + (j & 31) * 4 + p * 2;
  const uint4* krow0 = (const uint4*)(K4 + (size_t)r0 * (NROWS / 2));
  const uint4* krow1 = (const uint4*)(K4 + (size_t)(r0 + 1) * (NROWS / 2));
  const unsigned char* srow0 = scales + (size_t)r0 * 256;
  const unsigned char* srow1 = srow0 + 256;
  const uint4* x4 = (const uint4*)xin;
  const int b0 = h * 128 + lane;
  const int b1 = b0 + 64;

  uint4 xa0 = x4[b0 * 4 + 0], xb0 = x4[b0 * 4 + 1];
  uint4 xc0 = x4[b0 * 4 + 2], xd0 = x4[b0 * 4 + 3];
  uint4 xa1 = x4[b1 * 4 + 0], xb1 = x4[b1 * 4 + 1];
  uint4 xc1 = x4[b1 * 4 + 2], xd1 = x4[b1 * 4 + 3];
  uint4 k00 = krow0[b0], k01 = krow0[b1];
  uint4 k10 = krow1[b0], k11 = krow1[b1];
  uint32_t sb00 = srow0[b0], sb01 = srow0[b1];
  uint32_t sb10 = srow1[b0], sb11 = srow1[b1];

  float s1_0, s2_0, s1_1, s2_1;
  {
    float S = __uint_as_float(sb00 << 23);
    float lnS = ((float)(int)sb00 - 127.f) * 0.69314718f;
    float s1b = 0.f, t2b = 0.f;
    FINDOT(k00.x, xa0) FINDOT(k00.y, xb0) FINDOT(k00.z, xc0) FINDOT(k00.w, xd0)
    s1_0 = S * s1b;
    s2_0 = S * fmaf(lnS, s1b, t2b);
  }
  {
    float S = __uint_as_float(sb01 << 23);
    float lnS = ((float)(int)sb01 - 127.f) * 0.69314718f;
    float s1b = 0.f, t2b = 0.f;
    FINDOT(k01.x, xa1) FINDOT(k01.y, xb1) FINDOT(k01.z, xc1) FINDOT(k01.w, xd1)
    s1_0 = fmaf(S, s1b, s1_0);
    s2_0 = fmaf(S, fmaf(lnS, s1b, t2b), s2_0);
  }
  {
    float S = __uint_as_float(sb10 << 23);
    float lnS = ((float)(int)sb10 - 127.f) * 0.69314718f;
    float s1b = 0.f, t2b = 0.f;
    FINDOT(k10.x, xa0) FINDOT(k10.y, xb0) FINDOT(k10.z, xc0) FINDOT(k10.w, xd0)
    s1_1 = S * s1b;
    s2_1 = S * fmaf(lnS, s1b, t2b);
  }
  {
    float S = __uint_as_float(sb11 << 23);
    float lnS = ((float)(int)sb11 - 127.f) * 0.69314718f;
    float s1b = 0.f, t2b = 0.f;
    FINDOT(k11.x, xa1) FINDOT(k11.y, xb1) FINDOT(k11.z, xc1) FINDOT(k11.w, xd1)
    s1_1 = fmaf(S, s1b, s1_1);
    s2_1 = fmaf(S, fmaf(lnS, s1b, t2b), s2_1);
  }

  s1_0 = wave_reduce_add(s1_0);
  s2_0 = wave_reduce_add(s2_0);
  s1_1 = wave_reduce_add(s1_1);
  s2_1 = wave_reduce_add(s2_1);
  __shared__ float sred[4][4];
  if (lane == 0) {
    sred[w][0] = s1_0; sred[w][1] = s2_0; sred[w][2] = s1_1; sred[w][3] = s2_1;
  }
  __syncthreads();
  if (t == 0) {
    float acc = 0.f;
    #pragma unroll
    for (int pp = 0; pp < 2; ++pp)
      #pragma unroll
      for (int jj = 0; jj < 2; ++jj) {
        float s1 = sred[pp * 2 + 0][jj * 2 + 0] + sred[pp * 2 + 1][jj * 2 + 0];
        float s2 = sred[pp * 2 + 0][jj * 2 + 1] + sred[pp * 2 + 1][jj * 2 + 1];
        acc += s2 / s1;
      }
    partials[blockIdx.x] = (-EPS) * acc;
  }
}

__global__ __launch_bounds__(256) void reduce_kernel(
    const float* __restrict__ partials, float* __restrict__ out) {
  const int t = threadIdx.x;
  float s = 0.f;
  #pragma unroll
  for (int i = 0; i < 8; ++i) s += partials[t + i * 256];
  s = wave_reduce_add(s);
  __shared__ float red[4];
  int lane = t & 63, wid = t >> 6;
  if (lane == 0) red[wid] = s;
  __syncthreads();
  if (t == 0) out[0] = red[0] + red[1] + red[2] + red[3];
}

// ---------- launch ----------

extern "C" void kernel_launch(void* const* d_in, const int* in_sizes, int n_in,
                              void* d_out, int out_size, void* d_ws, size_t ws_size,
                              hipStream_t stream) {
  const float* P = (const float*)d_in[0];
  const float* Q = (const float*)d_in[1];
  float* out = (float*)d_out;

  char* ws = (char*)d_ws;
  unsigned char* K4     = (unsigned char*)ws;                    // 33554432 B
  unsigned char* scales = (unsigned char*)(ws + 33554432);       // 2097152 B
  float* rspart   = (float*)(ws + 35651584);                     // 4 MB -> ends 39845888
  float* p2       = (float*)(ws + 39845888);                     // 32 KB
  float* q2       = (float*)(ws + 39878656);                     // 32 KB
  float* partials = (float*)(ws + 39911424);                     // 2048 floats
  unsigned short* ub16 = (unsigned short*)(ws + 39919616);       // 16 KB
  unsigned short* vb16 = ub16 + NROWS;                           // 16 KB -> 39952384
  uint4* Pb = (uint4*)(ws + 39952384);                           // 1 MB (frag-swizzled)
  uint4* Qb = (uint4*)(ws + 41000960);                           // 1 MB -> 42049536

  rownorm_pack<<<512, 256, 0, stream>>>(P, Q, p2, q2, Pb, Qb);
  kgen_kernel<<<dim3(NROWS / 128, NROWS / 256), 1024, 0, stream>>>(
      Pb, Qb, p2, q2, K4, scales, rspart);
  v1_kernel<<<NROWS / 128, 128, 0, stream>>>(rspart, vb16);

  // Passes m=1..8 (m=0 fused into kgen rowsum): after m=8, vb16 holds v5.
  for (int m = 1; m < 9; ++m) {
    const unsigned short* xin = (m & 1) ? vb16 : ub16;
    unsigned short* yout      = (m & 1) ? ub16 : vb16;
    matvec_fp4<<<NROWS / 16, 256, 0, stream>>>(K4, scales, xin, yout);
  }

  final_fp4<<<NROWS / 4, 256, 0, stream>>>(K4, scales, vb16, partials);
  reduce_kernel<<<1, 256, 0, stream>>>(partials, out);
}

// Round 14
// 170.423 us; speedup vs baseline: 1.0238x; 1.0238x over previous
//
#include <hip/hip_runtime.h>
#include <hip/hip_fp16.h>
#include <stdint.h>

#define NROWS 8192
#define DIM 64
#define EPS 0.1f

typedef float f32x4 __attribute__((ext_vector_type(4)));
typedef short s16x8 __attribute__((ext_vector_type(8)));
typedef _Float16 h2 __attribute__((ext_vector_type(2)));

// ---------- helpers ----------

__device__ __forceinline__ float wave_reduce_add(float v) {
  #pragma unroll
  for (int off = 32; off > 0; off >>= 1) v += __shfl_down(v, off, 64);
  return v;
}

// pack two fp32 -> bf16x2 dword by truncation (1 v_perm); x -> low, y -> high.
__device__ __forceinline__ uint32_t pack_bf16_trunc(float x, float y) {
  return __builtin_amdgcn_perm(__float_as_uint(y), __float_as_uint(x), 0x07060302u);
}

// Column permutation: K4 stores columns in pi-order so kgen's per-lane nibbles
// are contiguous. pi shuffles only bits 0..5 (within a 64-col half-tile).
__device__ __forceinline__ int pi_idx(int i) {
  int r = i & 63;
  int tj = r >> 4, quad = (r >> 2) & 3, e = r & 3;
  return (i & ~63) | (quad * 16 + tj * 4 + e);
}

// ---------- fp4 e2m1 encode/decode (block-scaled, scale applied manually) ----

#if __has_builtin(__builtin_amdgcn_cvt_scalef32_pk_f16_fp4)
#define CVT4H(kd, sel) __builtin_amdgcn_cvt_scalef32_pk_f16_fp4((kd), 1.0f, (sel))
#else
__device__ __forceinline__ h2 cvt4h_fb(uint32_t kd, int sel) {
  uint32_t byt  = (kd >> (sel * 8)) & 0xFFu;
  uint32_t selv = (byt & 0xFu) | ((byt >> 4) << 16);
  uint32_t tb = __builtin_amdgcn_perm(0x46444240u, 0x3E3C3800u, selv);
  uint32_t d  = ((tb & 0xFFu) << 8) | ((tb & 0xFF0000u) << 8);
  return __builtin_bit_cast(h2, d);
}
#define CVT4H(kd, sel) cvt4h_fb((kd), (sel))
#endif

#if __has_builtin(__builtin_amdgcn_cvt_scalef32_pk_fp4_f32)
__device__ __forceinline__ uint32_t enc4(float q0, float q1, float q2, float q3) {
  uint32_t pk = __builtin_amdgcn_cvt_scalef32_pk_fp4_f32(0u, q0, q1, 1.0f, 0);
  pk = __builtin_amdgcn_cvt_scalef32_pk_fp4_f32(pk, q2, q3, 1.0f, 1);
  return pk & 0xFFFFu;
}
#else
__device__ __forceinline__ uint32_t enc1(float q) {
  float c = fminf(floorf(2.f * q + 0.5f), 4.f);
  c += (q > 2.5f) ? 1.f : 0.f;
  c += (q > 3.5f) ? 1.f : 0.f;
  return (uint32_t)c;
}
__device__ __forceinline__ uint32_t enc4(float q0, float q1, float q2, float q3) {
  return enc1(q0) | (enc1(q1) << 4) | (enc1(q2) << 8) | (enc1(q3) << 12);
}
#endif

// fast exp of -10*d: exp2(-10*log2(e)*d)
#if __has_builtin(__builtin_amdgcn_exp2f)
#define EXPD(d) __builtin_amdgcn_exp2f(-14.4269504089f * (d))
#else
#define EXPD(d) __expf(-10.0f * (d))
#endif

#define FP4DOT(kd, xv, acc)                                                          \
  acc = __builtin_amdgcn_fdot2(CVT4H((kd), 0), __builtin_bit_cast(h2, (xv).x), acc, false); \
  acc = __builtin_amdgcn_fdot2(CVT4H((kd), 1), __builtin_bit_cast(h2, (xv).y), acc, false); \
  acc = __builtin_amdgcn_fdot2(CVT4H((kd), 2), __builtin_bit_cast(h2, (xv).z), acc, false); \
  acc = __builtin_amdgcn_fdot2(CVT4H((kd), 3), __builtin_bit_cast(h2, (xv).w), acc, false);

// final-pass dot: s1b += k^*x via CVT; t2b += (k^*ln k^)*x via exact-f16 nibble LUT.
#define FIN1(kd, xd_, sel)                                                           \
  {                                                                                  \
    uint32_t byt  = ((kd) >> ((sel) * 8)) & 0xFFu;                                   \
    uint32_t selv = (byt & 0xFu) | ((byt & 0xF0u) << 12);                            \
    uint32_t hi = __builtin_amdgcn_perm(0x4945423Du, 0x3800B500u, selv);             \
    uint32_t lo = __builtin_amdgcn_perm(0x608C978Cu, 0xDE008C00u, selv);             \
    h2 lut = __builtin_bit_cast(h2, lo | (hi << 8));                                 \
    h2 xp  = __builtin_bit_cast(h2, (xd_));                                          \
    s1b = __builtin_amdgcn_fdot2(CVT4H((kd), (sel)), xp, s1b, false);                \
    t2b = __builtin_amdgcn_fdot2(lut, xp, t2b, false);                               \
  }
#define FINDOT(kd, xv) FIN1(kd, (xv).x, 0) FIN1(kd, (xv).y, 1) FIN1(kd, (xv).z, 2) FIN1(kd, (xv).w, 3)

// ---------- rownorm_pack: |row|^2 AND fragment-swizzled bf16 rows --------------
// Pb/Qb layout (1 MB each): chunk (row r, kc c) = 16 B at uint4 index
// ((r>>4)*8 + c)*16 + (r&15) — MFMA fragment order, loaded straight from global.

__global__ __launch_bounds__(256) void rownorm_pack(
    const float* __restrict__ P, const float* __restrict__ Q,
    float* __restrict__ p2, float* __restrict__ q2,
    uint4* __restrict__ Pb, uint4* __restrict__ Qb) {
  int g = blockIdx.x * 256 + threadIdx.x;   // 131072 threads
  int row = g >> 3, sub = g & 7;            // row 0..16383, chunk sub 0..7
  const float* X;
  float* out;
  uint4* Xb;
  int r;
  float sc;
  if (row < NROWS) { X = P; out = p2; Xb = Pb; r = row; sc = -2.f; }
  else             { X = Q; out = q2; Xb = Qb; r = row - NROWS; sc = 1.f; }
  const float4* X4 = (const float4*)(X + (size_t)r * DIM);
  float4 a0 = X4[sub * 2], a1 = X4[sub * 2 + 1];
  float ss = a0.x * a0.x + a0.y * a0.y + a0.z * a0.z + a0.w * a0.w
           + a1.x * a1.x + a1.y * a1.y + a1.z * a1.z + a1.w * a1.w;
  ss += __shfl_xor(ss, 1, 64);
  ss += __shfl_xor(ss, 2, 64);
  ss += __shfl_xor(ss, 4, 64);
  if (sub == 0) out[r] = ss;
  uint4 pk;
  pk.x = pack_bf16_trunc(sc * a0.x, sc * a0.y);
  pk.y = pack_bf16_trunc(sc * a0.z, sc * a0.w);
  pk.z = pack_bf16_trunc(sc * a1.x, sc * a1.y);
  pk.w = pack_bf16_trunc(sc * a1.z, sc * a1.w);
  Xb[(((r >> 4) * 8 + sub) << 4) + (r & 15)] = pk;
}

// ---------- kgen: LDS-FREE MFMA bf16 -> fp4 K + e8m0 scales --------------------
// Fragments loaded directly from fragment-swizzled Pb/Qb (L2-hot, 2 MB total):
// no LDS, no __syncthreads -> waves fully independent, occupancy not LDS-capped.
// Grid (row-panels=64 x-fastest, col-panels=32): K4 row-striped per XCD L2.
// (Round-13 A/B: 1024-thr/32x64-wave variant was -3 us — this 512-thr form wins.)

__global__ __launch_bounds__(512) void kgen_kernel(
    const uint4* __restrict__ Pb, const uint4* __restrict__ Qb,
    const float* __restrict__ p2, const float* __restrict__ q2,
    unsigned char* __restrict__ K4, unsigned char* __restrict__ scales,
    float* __restrict__ rspart) {
  const int t  = threadIdx.x;
  const int bi = blockIdx.x * 128;   // row panel (x-fastest -> XCD = panel%8)
  const int bj = blockIdx.y * 256;   // col panel

  const int w        = t >> 6;
  const int lane     = t & 63;
  const int quad     = lane >> 4;
  const int m16      = lane & 15;
  const int wave_row = (w >> 2) * 64;        // 0 or 64
  const int wave_col = (w & 3) * 64;         // 0,64,128,192

  const s16x8* Pw = (const s16x8*)Pb;
  const s16x8* Qw = (const s16x8*)Qb;
  const int gp = (bi + wave_row) >> 4;       // 16-row group base
  const int gq = (bj + wave_col) >> 4;

  float pn[4];
  f32x4 qn[4];
  #pragma unroll
  for (int ti = 0; ti < 4; ++ti) pn[ti] = p2[bi + wave_row + ti * 16 + m16];
  #pragma unroll
  for (int tj = 0; tj < 4; ++tj)
    qn[tj] = *(const f32x4*)&q2[bj + wave_col + tj * 16 + quad * 4];

  f32x4 acc[4][4];
  #pragma unroll
  for (int ti = 0; ti < 4; ++ti)
    #pragma unroll
    for (int tj = 0; tj < 4; ++tj) acc[ti][tj] = qn[tj] + pn[ti];

  #pragma unroll
  for (int kstep = 0; kstep < 2; ++kstep) {
    const int kc = kstep * 4 + quad;
    s16x8 af[4], bf[4];
    #pragma unroll
    for (int ti = 0; ti < 4; ++ti)
      af[ti] = Pw[((gp + ti) * 8 + kc) * 16 + m16];
    #pragma unroll
    for (int tj = 0; tj < 4; ++tj)
      bf[tj] = Qw[((gq + tj) * 8 + kc) * 16 + m16];
    #pragma unroll
    for (int ti = 0; ti < 4; ++ti)
      #pragma unroll
      for (int tj = 0; tj < 4; ++tj)
        acc[ti][tj] = __builtin_amdgcn_mfma_f32_16x16x32_bf16(
            bf[tj], af[ti], acc[ti][tj], 0, 0, 0);   // swapped operands
  }

  #pragma unroll
  for (int ti = 0; ti < 4; ++ti) {
    const int row = bi + wave_row + ti * 16 + m16;
    float kv[4][4];
    float mx = 0.f, rs = 0.f;
    #pragma unroll
    for (int tj = 0; tj < 4; ++tj) {
      f32x4 sq = acc[ti][tj];
      kv[tj][0] = EXPD(__builtin_amdgcn_sqrtf(fmaxf(sq.x, 0.f)));
      kv[tj][1] = EXPD(__builtin_amdgcn_sqrtf(fmaxf(sq.y, 0.f)));
      kv[tj][2] = EXPD(__builtin_amdgcn_sqrtf(fmaxf(sq.z, 0.f)));
      kv[tj][3] = EXPD(__builtin_amdgcn_sqrtf(fmaxf(sq.w, 0.f)));
      float mt = fmaxf(fmaxf(kv[tj][0], kv[tj][1]), fmaxf(kv[tj][2], kv[tj][3]));
      mx = fmaxf(mx, mt);
      rs += (kv[tj][0] + kv[tj][1]) + (kv[tj][2] + kv[tj][3]);
    }
    mx = fmaxf(mx, __shfl_xor(mx, 16, 64));
    uint32_t eb = (__float_as_uint(mx) >> 23) - 1u;
    float si = __uint_as_float((254u - eb) << 23);   // 1/S, S = 2^(e-1)
    uint32_t pk0 = enc4(kv[0][0] * si, kv[0][1] * si, kv[0][2] * si, kv[0][3] * si);
    uint32_t pk1 = enc4(kv[1][0] * si, kv[1][1] * si, kv[1][2] * si, kv[1][3] * si);
    uint32_t pk2 = enc4(kv[2][0] * si, kv[2][1] * si, kv[2][2] * si, kv[2][3] * si);
    uint32_t pk3 = enc4(kv[3][0] * si, kv[3][1] * si, kv[3][2] * si, kv[3][3] * si);
    uint2 st = uint2{pk0 | (pk1 << 16), pk2 | (pk3 << 16)};
    *(uint2*)(K4 + (size_t)row * (NROWS / 2) + ((bj + wave_col) >> 1) + quad * 8) = st;
    uint32_t eb2 = (uint32_t)__shfl_xor((int)eb, 32, 64);  // quad0 <- quad2
    if (quad == 0) {
      *(unsigned short*)(scales + (size_t)row * 256 + ((bj + wave_col) >> 5)) =
          (unsigned short)((eb & 0xFFu) | ((eb2 & 0xFFu) << 8));
    }
    float v = rs;
    v += __shfl_xor(v, 16, 64);
    v += __shfl_xor(v, 32, 64);
    if (quad == 0)
      rspart[(size_t)(blockIdx.y * 4 + (w & 3)) * NROWS + row] = v;
  }
}

// v1: reduce 128 rowsum partials per row; vb16[pi(i)] = f16(64 / rowsum[i])
__global__ __launch_bounds__(128) void v1_kernel(const float* __restrict__ rspart,
                                                 unsigned short* __restrict__ vb16) {
  int i = blockIdx.x * 128 + threadIdx.x;
  float s = 0.f;
  #pragma unroll 8
  for (int c = 0; c < 128; ++c) s += rspart[(size_t)c * NROWS + i];
  vb16[pi_idx(i)] = __half_as_ushort(__float2half(64.0f / s));
}

// ---------- matvec: 4 rows x all cols per wave; rows remapped so each block's
// K-panel lives in ITS XCD's L2 (block b -> row panel p with p%8 == b%8) -------

__global__ __launch_bounds__(256) void matvec_fp4(
    const unsigned char* __restrict__ K4, const unsigned char* __restrict__ scales,
    const unsigned short* __restrict__ xin, unsigned short* __restrict__ yout) {
  const int t = threadIdx.x, lane = t & 63, w = t >> 6;
  const int bk = blockIdx.x & 7, j = blockIdx.x >> 3;       // XCD class, intra
  const int panel = ((j >> 3) << 3) | bk;                   // panel%8 == bk
  const int r0 = panel * 128 + (j & 7) * 16 + w * 4;
  const uint4* kr0 = (const uint4*)(K4 + (size_t)r0 * (NROWS / 2));
  const uint4* kr1 = (const uint4*)(K4 + (size_t)(r0 + 1) * (NROWS / 2));
  const uint4* kr2 = (const uint4*)(K4 + (size_t)(r0 + 2) * (NROWS / 2));
  const uint4* kr3 = (const uint4*)(K4 + (size_t)(r0 + 3) * (NROWS / 2));
  const unsigned char* sr0 = scales + (size_t)r0 * 256;
  const unsigned char* sr1 = sr0 + 256;
  const unsigned char* sr2 = sr0 + 512;
  const unsigned char* sr3 = sr0 + 768;
  const uint4* x4 = (const uint4*)xin;

  // chunk 0 preload
  int b = lane;
  uint4 nx0 = x4[b * 4 + 0], nx1 = x4[b * 4 + 1];
  uint4 nx2 = x4[b * 4 + 2], nx3 = x4[b * 4 + 3];
  uint4 nk0 = kr0[b], nk1 = kr1[b], nk2 = kr2[b], nk3 = kr3[b];

  float t0 = 0.f, t1 = 0.f, t2 = 0.f, t3 = 0.f;
  #pragma unroll
  for (int s = 0; s < 4; ++s) {
    uint4 cx0 = nx0, cx1 = nx1, cx2 = nx2, cx3 = nx3;
    uint4 ck0 = nk0, ck1 = nk1, ck2 = nk2, ck3 = nk3;
    uint32_t sb0 = sr0[b], sb1 = sr1[b], sb2 = sr2[b], sb3 = sr3[b];
    if (s < 3) {
      int bn = b + 64;
      nx0 = x4[bn * 4 + 0]; nx1 = x4[bn * 4 + 1];
      nx2 = x4[bn * 4 + 2]; nx3 = x4[bn * 4 + 3];
      nk0 = kr0[bn]; nk1 = kr1[bn]; nk2 = kr2[bn]; nk3 = kr3[bn];
      b = bn;
    }
    float a0, a1;
    a0 = 0.f; a1 = 0.f;
    FP4DOT(ck0.x, cx0, a0) FP4DOT(ck0.y, cx1, a1)
    FP4DOT(ck0.z, cx2, a0) FP4DOT(ck0.w, cx3, a1)
    t0 = fmaf(__uint_as_float(sb0 << 23), a0 + a1, t0);
    a0 = 0.f; a1 = 0.f;
    FP4DOT(ck1.x, cx0, a0) FP4DOT(ck1.y, cx1, a1)
    FP4DOT(ck1.z, cx2, a0) FP4DOT(ck1.w, cx3, a1)
    t1 = fmaf(__uint_as_float(sb1 << 23), a0 + a1, t1);
    a0 = 0.f; a1 = 0.f;
    FP4DOT(ck2.x, cx0, a0) FP4DOT(ck2.y, cx1, a1)
    FP4DOT(ck2.z, cx2, a0) FP4DOT(ck2.w, cx3, a1)
    t2 = fmaf(__uint_as_float(sb2 << 23), a0 + a1, t2);
    a0 = 0.f; a1 = 0.f;
    FP4DOT(ck3.x, cx0, a0) FP4DOT(ck3.y, cx1, a1)
    FP4DOT(ck3.z, cx2, a0) FP4DOT(ck3.w, cx3, a1)
    t3 = fmaf(__uint_as_float(sb3 << 23), a0 + a1, t3);
  }

  t0 = wave_reduce_add(t0);
  t1 = wave_reduce_add(t1);
  t2 = wave_reduce_add(t2);
  t3 = wave_reduce_add(t3);
  if (lane == 0) {
    yout[pi_idx(r0 + 0)] = __half_as_ushort(__float2half(1.0f / t0));
    yout[pi_idx(r0 + 1)] = __half_as_ushort(__float2half(1.0f / t1));
    yout[pi_idx(r0 + 2)] = __half_as_ushort(__float2half(1.0f / t2));
    yout[pi_idx(r0 + 3)] = __half_as_ushort(__float2half(1.0f / t3));
  }
}

// ---------- final_fp4: 2 rows x half-cols per wave, XCD-remapped rows ----------

__global__ __launch_bounds__(256) void final_fp4(
    const unsigned char* __restrict__ K4, const unsigned char* __restrict__ scales,
    const unsigned short* __restrict__ xin, float* __restrict__ partials) {
  const int t = threadIdx.x, lane = t & 63, w = t >> 6;
  const int p = w >> 1, h = w & 1;
  const int bk = blockIdx.x & 7, j = blockIdx.x >> 3;       // j 0..255
  const int panel = ((j >> 5) << 3) | bk;                   // panel%8 == bk
  const int r0 = panel * 128 + (j & 31) * 4 + p * 2;
  const uint4* krow0 = (const uint4*)(K4 + (size_t)r0 * (NROWS / 2));
  const uint4* krow1 = (const uint4*)(K4 + (size_t)(r0 + 1) * (NROWS / 2));
  const unsigned char* srow0 = scales + (size_t)r0 * 256;
  const unsigned char* srow1 = srow0 + 256;
  const uint4* x4 = (const uint4*)xin;
  const int b0 = h * 128 + lane;
  const int b1 = b0 + 64;

  uint4 xa0 = x4[b0 * 4 + 0], xb0 = x4[b0 * 4 + 1];
  uint4 xc0 = x4[b0 * 4 + 2], xd0 = x4[b0 * 4 + 3];
  uint4 xa1 = x4[b1 * 4 + 0], xb1 = x4[b1 * 4 + 1];
  uint4 xc1 = x4[b1 * 4 + 2], xd1 = x4[b1 * 4 + 3];
  uint4 k00 = krow0[b0], k01 = krow0[b1];
  uint4 k10 = krow1[b0], k11 = krow1[b1];
  uint32_t sb00 = srow0[b0], sb01 = srow0[b1];
  uint32_t sb10 = srow1[b0], sb11 = srow1[b1];

  float s1_0, s2_0, s1_1, s2_1;
  {
    float S = __uint_as_float(sb00 << 23);
    float lnS = ((float)(int)sb00 - 127.f) * 0.69314718f;
    float s1b = 0.f, t2b = 0.f;
    FINDOT(k00.x, xa0) FINDOT(k00.y, xb0) FINDOT(k00.z, xc0) FINDOT(k00.w, xd0)
    s1_0 = S * s1b;
    s2_0 = S * fmaf(lnS, s1b, t2b);
  }
  {
    float S = __uint_as_float(sb01 << 23);
    float lnS = ((float)(int)sb01 - 127.f) * 0.69314718f;
    float s1b = 0.f, t2b = 0.f;
    FINDOT(k01.x, xa1) FINDOT(k01.y, xb1) FINDOT(k01.z, xc1) FINDOT(k01.w, xd1)
    s1_0 = fmaf(S, s1b, s1_0);
    s2_0 = fmaf(S, fmaf(lnS, s1b, t2b), s2_0);
  }
  {
    float S = __uint_as_float(sb10 << 23);
    float lnS = ((float)(int)sb10 - 127.f) * 0.69314718f;
    float s1b = 0.f, t2b = 0.f;
    FINDOT(k10.x, xa0) FINDOT(k10.y, xb0) FINDOT(k10.z, xc0) FINDOT(k10.w, xd0)
    s1_1 = S * s1b;
    s2_1 = S * fmaf(lnS, s1b, t2b);
  }
  {
    float S = __uint_as_float(sb11 << 23);
    float lnS = ((float)(int)sb11 - 127.f) * 0.69314718f;
    float s1b = 0.f, t2b = 0.f;
    FINDOT(k11.x, xa1) FINDOT(k11.y, xb1) FINDOT(k11.z, xc1) FINDOT(k11.w, xd1)
    s1_1 = fmaf(S, s1b, s1_1);
    s2_1 = fmaf(S, fmaf(lnS, s1b, t2b), s2_1);
  }

  s1_0 = wave_reduce_add(s1_0);
  s2_0 = wave_reduce_add(s2_0);
  s1_1 = wave_reduce_add(s1_1);
  s2_1 = wave_reduce_add(s2_1);
  __shared__ float sred[4][4];
  if (lane == 0) {
    sred[w][0] = s1_0; sred[w][1] = s2_0; sred[w][2] = s1_1; sred[w][3] = s2_1;
  }
  __syncthreads();
  if (t == 0) {
    float acc = 0.f;
    #pragma unroll
    for (int pp = 0; pp < 2; ++pp)
      #pragma unroll
      for (int jj = 0; jj < 2; ++jj) {
        float s1 = sred[pp * 2 + 0][jj * 2 + 0] + sred[pp * 2 + 1][jj * 2 + 0];
        float s2 = sred[pp * 2 + 0][jj * 2 + 1] + sred[pp * 2 + 1][jj * 2 + 1];
        acc += s2 / s1;
      }
    partials[blockIdx.x] = (-EPS) * acc;
  }
}

__global__ __launch_bounds__(256) void reduce_kernel(
    const float* __restrict__ partials, float* __restrict__ out) {
  const int t = threadIdx.x;
  float s = 0.f;
  #pragma unroll
  for (int i = 0; i < 8; ++i) s += partials[t + i * 256];
  s = wave_reduce_add(s);
  __shared__ float red[4];
  int lane = t & 63, wid = t >> 6;
  if (lane == 0) red[wid] = s;
  __syncthreads();
  if (t == 0) out[0] = red[0] + red[1] + red[2] + red[3];
}

// ---------- launch ----------

extern "C" void kernel_launch(void* const* d_in, const int* in_sizes, int n_in,
                              void* d_out, int out_size, void* d_ws, size_t ws_size,
                              hipStream_t stream) {
  const float* P = (const float*)d_in[0];
  const float* Q = (const float*)d_in[1];
  float* out = (float*)d_out;

  char* ws = (char*)d_ws;
  unsigned char* K4     = (unsigned char*)ws;                    // 33554432 B
  unsigned char* scales = (unsigned char*)(ws + 33554432);       // 2097152 B
  float* rspart   = (float*)(ws + 35651584);                     // 4 MB -> ends 39845888
  float* p2       = (float*)(ws + 39845888);                     // 32 KB
  float* q2       = (float*)(ws + 39878656);                     // 32 KB
  float* partials = (float*)(ws + 39911424);                     // 2048 floats
  unsigned short* ub16 = (unsigned short*)(ws + 39919616);       // 16 KB
  unsigned short* vb16 = ub16 + NROWS;                           // 16 KB -> 39952384
  uint4* Pb = (uint4*)(ws + 39952384);                           // 1 MB (frag-swizzled)
  uint4* Qb = (uint4*)(ws + 41000960);                           // 1 MB -> 42049536

  rownorm_pack<<<512, 256, 0, stream>>>(P, Q, p2, q2, Pb, Qb);
  kgen_kernel<<<dim3(NROWS / 128, NROWS / 256), 512, 0, stream>>>(
      Pb, Qb, p2, q2, K4, scales, rspart);
  v1_kernel<<<NROWS / 128, 128, 0, stream>>>(rspart, vb16);

  // Passes m=1..8 (m=0 fused into kgen rowsum): after m=8, vb16 holds v5.
  for (int m = 1; m < 9; ++m) {
    const unsigned short* xin = (m & 1) ? vb16 : ub16;
    unsigned short* yout      = (m & 1) ? ub16 : vb16;
    matvec_fp4<<<NROWS / 16, 256, 0, stream>>>(K4, scales, xin, yout);
  }

  final_fp4<<<NROWS / 4, 256, 0, stream>>>(K4, scales, vb16, partials);
  reduce_kernel<<<1, 256, 0, stream>>>(partials, out);
}